// Round 9
// baseline (1030.904 us; speedup 1.0000x reference)
//
#include <hip/hip_runtime.h>
#include <stdint.h>

#define DEV __device__ __forceinline__

using f32x4  = __attribute__((ext_vector_type(4))) float;
using bf16x8 = __attribute__((ext_vector_type(8))) short;
typedef unsigned short u16;
typedef unsigned int   u32;

typedef const __attribute__((address_space(1))) void* gptr_t;
typedef __attribute__((address_space(3))) void*       lptr_t;

DEV u16 f2bf(float f) {               // RTNE float -> bf16 bits
  union { float f; u32 u; } v; v.f = f;
  u32 lsb = (v.u >> 16) & 1u;
  v.u += 0x7fffu + lsb;
  return (u16)(v.u >> 16);
}
DEV float bf2f(u16 h) {
  union { u32 u; float f; } v; v.u = ((u32)h) << 16;
  return v.f;
}
DEV void async16(void* lds, const void* g) {
  __builtin_amdgcn_global_load_lds((gptr_t)(uintptr_t)g,
                                   (lptr_t)(u32)(uintptr_t)lds, 16, 0, 0);
}
// monotone float->uint key (ascending order preserved)
DEV u32 fkey(float v) {
  u32 u = __float_as_uint(v);
  return u ^ ((u & 0x80000000u) ? 0xFFFFFFFFu : 0x80000000u);
}
DEV float unfkey(u32 key) {
  const u32 ub = (key & 0x80000000u) ? (key ^ 0x80000000u) : ~key;
  return __uint_as_float(ub);
}

// bit-exact replica of np.einsum fp32 inner dot (sum_of_products_contig_outstride0_two,
// SSE-128 baseline, no FMA): 4 lanes (j === l mod 4); per 16-block reversed chain;
// combine (v0+v1)+(v2+v3) via SSE3 hadd. 1024 = 64 blocks, no tail. [R6-validated]
DEV float replica_dot(const float* __restrict__ xr, const float* __restrict__ wr) {
  float v0 = 0.f, v1 = 0.f, v2 = 0.f, v3 = 0.f;
  for (int j = 0; j < 1024; j += 16) {
    float t0 = __fadd_rn(__fmul_rn(xr[j + 12], wr[j + 12]), v0);
    float t1 = __fadd_rn(__fmul_rn(xr[j + 13], wr[j + 13]), v1);
    float t2 = __fadd_rn(__fmul_rn(xr[j + 14], wr[j + 14]), v2);
    float t3 = __fadd_rn(__fmul_rn(xr[j + 15], wr[j + 15]), v3);
    t0 = __fadd_rn(__fmul_rn(xr[j + 8],  wr[j + 8]),  t0);
    t1 = __fadd_rn(__fmul_rn(xr[j + 9],  wr[j + 9]),  t1);
    t2 = __fadd_rn(__fmul_rn(xr[j + 10], wr[j + 10]), t2);
    t3 = __fadd_rn(__fmul_rn(xr[j + 11], wr[j + 11]), t3);
    t0 = __fadd_rn(__fmul_rn(xr[j + 4],  wr[j + 4]),  t0);
    t1 = __fadd_rn(__fmul_rn(xr[j + 5],  wr[j + 5]),  t1);
    t2 = __fadd_rn(__fmul_rn(xr[j + 6],  wr[j + 6]),  t2);
    t3 = __fadd_rn(__fmul_rn(xr[j + 7],  wr[j + 7]),  t3);
    v0 = __fadd_rn(__fmul_rn(xr[j + 0],  wr[j + 0]),  t0);
    v1 = __fadd_rn(__fmul_rn(xr[j + 1],  wr[j + 1]),  t1);
    v2 = __fadd_rn(__fmul_rn(xr[j + 2],  wr[j + 2]),  t2);
    v3 = __fadd_rn(__fmul_rn(xr[j + 3],  wr[j + 3]),  t3);
  }
  return __fadd_rn(__fadd_rn(v0, v1), __fadd_rn(v2, v3));
}

// ---------------- split kernel: fp32 -> bf16 ----------------
__global__ __launch_bounds__(256) void split1_kernel(const float* __restrict__ src,
                                                     u16* __restrict__ hi, int n) {
  int i = blockIdx.x * 256 + threadIdx.x;
  if (i >= n) return;
  hi[i] = f2bf(src[i]);
}

// XCD-aware block swizzle (nwg % 8 == 0 for all our grids)
DEV void swz_block(int& bx, int& by) {
  const int gx = gridDim.x, nwg = gx * gridDim.y;
  const int lid = by * gx + bx;
  const int cpx = nwg >> 3;
  const int swz = (lid & 7) * cpx + (lid >> 3);
  bx = swz % gx; by = swz / gx;
}

// ------- GEMM 1-pass bf16: C = A*B^T fp32 out (z / gate) -------
template<int BK>
__global__ __launch_bounds__(256) void gemm_bt(
    const u16* __restrict__ A, const u16* __restrict__ B,
    float* __restrict__ C, int N, int K)
{
  constexpr int TILE = 128 * BK;
  __shared__ u16 smem[2 * TILE];
  u16* sA = smem;
  u16* sB = smem + TILE;

  const int tid  = threadIdx.x;
  const int lane = tid & 63;
  const int wave = tid >> 6;
  const int wr = wave >> 1, wc = wave & 1;
  int bx = blockIdx.x, by = blockIdx.y;
  swz_block(bx, by);
  const int m0 = by * 128, n0 = bx * 128;

  f32x4 acc[4][4] = {};
  constexpr int SPR   = BK / 8;
  constexpr int ITERS = (128 * SPR) / 256;

  for (int k0 = 0; k0 < K; k0 += BK) {
#pragma unroll
    for (int i = 0; i < ITERS; ++i) {
      const int slot = i * 256 + tid;
      const int r = slot / SPR, cc = slot % SPR;
      const int uni = (i * 256 + wave * 64) * 8;
      async16(sA + uni, A + (size_t)(m0 + r) * K + k0 + cc * 8);
      async16(sB + uni, B + (size_t)(n0 + r) * K + k0 + cc * 8);
    }
    __syncthreads();

#pragma unroll
    for (int ks = 0; ks < BK / 32; ++ks) {
      const int kb = ks * 32 + (lane >> 4) * 8;
      bf16x8 a[4], b[4];
#pragma unroll
      for (int i = 0; i < 4; ++i) {
        a[i] = *(const bf16x8*)&sA[(wr * 64 + i * 16 + (lane & 15)) * BK + kb];
        b[i] = *(const bf16x8*)&sB[(wc * 64 + i * 16 + (lane & 15)) * BK + kb];
      }
#pragma unroll
      for (int mi = 0; mi < 4; ++mi)
#pragma unroll
        for (int ni = 0; ni < 4; ++ni)
          acc[mi][ni] = __builtin_amdgcn_mfma_f32_16x16x32_bf16(a[mi], b[ni], acc[mi][ni], 0, 0, 0);
    }
    __syncthreads();
  }

#pragma unroll
  for (int mi = 0; mi < 4; ++mi) {
    const int rbase = m0 + wr * 64 + mi * 16 + (lane >> 4) * 4;
#pragma unroll
    for (int ni = 0; ni < 4; ++ni) {
      const int col = n0 + wc * 64 + ni * 16 + (lane & 15);
#pragma unroll
      for (int r2 = 0; r2 < 4; ++r2)
        C[(size_t)(rbase + r2) * N + col] = acc[mi][ni][r2];
    }
  }
}

// ------- down GEMM, 2-segment split-A: C = [Ahi|Alo] . [B|B] over K'=2K -------
// Removes the bf16-quantization of s from the output error (A = s fp32-faithful).
template<int BK>
__global__ __launch_bounds__(256) void gemm2s_kernel(
    const u16* __restrict__ Ahi, const u16* __restrict__ Alo,
    const u16* __restrict__ B, float* __restrict__ C, int N, int K)
{
  constexpr int TILE = 128 * BK;
  __shared__ u16 smem[2 * TILE];
  u16* sA = smem;
  u16* sB = smem + TILE;

  const int tid  = threadIdx.x;
  const int lane = tid & 63;
  const int wave = tid >> 6;
  const int wr = wave >> 1, wc = wave & 1;
  int bx = blockIdx.x, by = blockIdx.y;
  swz_block(bx, by);
  const int m0 = by * 128, n0 = bx * 128;

  f32x4 acc[4][4] = {};
  constexpr int SPR   = BK / 8;
  constexpr int ITERS = (128 * SPR) / 256;

  for (int kt = 0; kt < 2 * K; kt += BK) {
    const int seg = (kt >= K) ? 1 : 0;
    const int kl  = kt - seg * K;
    const u16* __restrict__ Asrc = seg ? Alo : Ahi;
#pragma unroll
    for (int i = 0; i < ITERS; ++i) {
      const int slot = i * 256 + tid;
      const int r = slot / SPR, cc = slot % SPR;
      const int uni = (i * 256 + wave * 64) * 8;
      async16(sA + uni, Asrc + (size_t)(m0 + r) * K + kl + cc * 8);
      async16(sB + uni, B + (size_t)(n0 + r) * K + kl + cc * 8);
    }
    __syncthreads();

#pragma unroll
    for (int ks = 0; ks < BK / 32; ++ks) {
      const int kb = ks * 32 + (lane >> 4) * 8;
      bf16x8 a[4], b[4];
#pragma unroll
      for (int i = 0; i < 4; ++i) {
        a[i] = *(const bf16x8*)&sA[(wr * 64 + i * 16 + (lane & 15)) * BK + kb];
        b[i] = *(const bf16x8*)&sB[(wc * 64 + i * 16 + (lane & 15)) * BK + kb];
      }
#pragma unroll
      for (int mi = 0; mi < 4; ++mi)
#pragma unroll
        for (int ni = 0; ni < 4; ++ni)
          acc[mi][ni] = __builtin_amdgcn_mfma_f32_16x16x32_bf16(a[mi], b[ni], acc[mi][ni], 0, 0, 0);
    }
    __syncthreads();
  }

#pragma unroll
  for (int mi = 0; mi < 4; ++mi) {
    const int rbase = m0 + wr * 64 + mi * 16 + (lane >> 4) * 4;
#pragma unroll
    for (int ni = 0; ni < 4; ++ni) {
      const int col = n0 + wc * 64 + ni * 16 + (lane & 15);
#pragma unroll
      for (int r2 = 0; r2 < 4; ++r2)
        C[(size_t)(rbase + r2) * N + col] = acc[mi][ni][r2];
    }
  }
}

// ---------------- per-row top-k: wide band on 1-pass z + replica keys ----------------
// z from 1-pass bf16 GEMM: |z - z_numpy| <= 7.5e-3 (Hoeffding, P_fail ~ 1e-18 overall).
// 20-step bisection -> tau (quantum 2.4e-4). Band |z-tau| <= 1.5e-2 covers every
// channel whose ref-selection could differ; band gets bit-exact numpy-replica act
// keys; D = {z-tau > band} definite. Invariants D < k <= D + nb hold by construction.
// Writes s as bf16 hi/lo pair (fp32-faithful A for the 2-segment down GEMM).
__global__ __launch_bounds__(256) void select5_kernel(
    const float* __restrict__ z, const float* __restrict__ g,
    const float* __restrict__ xin, const float* __restrict__ W1,
    u16* __restrict__ s_hi, u16* __restrict__ s_lo,
    const int* __restrict__ kptr)
{
  const int row = blockIdx.x, tid = threadIdx.x;
  const int lane = tid & 63, wave = tid >> 6;
  const int k = *kptr;

  __shared__ float xrow[1024];
  __shared__ float sact[4096];
  __shared__ int wsum[21][4];
  __shared__ unsigned char flag[4096];
  __shared__ int s_nb;
  __shared__ int band_idx[256];
  __shared__ u32 band_key[256];

  // this thread's 16 z values + keys
  float zreg[16];
  u32 kreg[16];
  const float* zr = z + (size_t)row * 4096;
#pragma unroll
  for (int i = 0; i < 4; ++i) {
    const float4 v = *(const float4*)&zr[i * 1024 + tid * 4];
    zreg[i * 4 + 0] = v.x; zreg[i * 4 + 1] = v.y;
    zreg[i * 4 + 2] = v.z; zreg[i * 4 + 3] = v.w;
  }
#pragma unroll
  for (int i = 0; i < 16; ++i) kreg[i] = fkey(zreg[i]);

  for (int j = tid; j < 1024; j += 256) xrow[j] = xin[(size_t)row * 1024 + j];
  for (int f = tid; f < 4096; f += 256) flag[f] = 0;
  if (tid == 0) s_nb = 0;
  __syncthreads();

  // 20-step MSB bisection (bits 31..12) for ~kth largest key
  u32 prefix = 0;
  for (int step = 0; step < 20; ++step) {
    const int bit = 31 - step;
    const u32 c = prefix | (1u << bit);
    int cnt = 0;
#pragma unroll
    for (int i = 0; i < 16; ++i) cnt += (kreg[i] >= c) ? 1 : 0;
    for (int off = 32; off; off >>= 1) cnt += __shfl_xor(cnt, off);
    if (lane == 0) wsum[step][wave] = cnt;
    __syncthreads();
    const int tot = wsum[step][0] + wsum[step][1] + wsum[step][2] + wsum[step][3];
    if (tot >= k) prefix = c;
  }
  const float tau = unfkey(prefix);
  const float BANDW = 1.5e-2f;

  // D flags (definite-selected), band gather, |D| count
  int cntD = 0;
#pragma unroll
  for (int i = 0; i < 16; ++i) {
    const int f = (i >> 2) * 1024 + tid * 4 + (i & 3);
    const float d = zreg[i] - tau;
    if (d > BANDW) { flag[f] = 1; ++cntD; }
    else if (d >= -BANDW) {
      const int p = atomicAdd(&s_nb, 1);
      if (p < 256) band_idx[p] = f;
    }
  }
  for (int off = 32; off; off >>= 1) cntD += __shfl_xor(cntD, off);
  if (lane == 0) wsum[20][wave] = cntD;
  __syncthreads();
  const int D = wsum[20][0] + wsum[20][1] + wsum[20][2] + wsum[20][3];
  const int nb = (s_nb < 256) ? s_nb : 256;
  const int need = k - D;

  // exact numpy-replica act keys for band channels
  for (int i = tid; i < nb; i += 256) {
    const int f = band_idx[i];
    const float zrep = replica_dot(xrow, W1 + (size_t)f * 1024);
    const double zd = (double)zrep;
    const float a = (float)(zd / (1.0 + exp(-zd)));
    sact[f] = a;
    band_key[i] = fkey(a);
  }
  __syncthreads();

  // stable rank (exact key desc, index asc); select rank < need
  for (int i = tid; i < nb; i += 256) {
    const u32 ki = band_key[i];
    const int fi = band_idx[i];
    int rank = 0;
    for (int j = 0; j < nb; ++j) {
      const u32 kj = band_key[j];
      rank += (kj > ki || (kj == ki && band_idx[j] < fi)) ? 1 : 0;
    }
    if (rank < need) flag[fi] = 2;
  }
  __syncthreads();

  // write s = act * gate (bf16 hi/lo pair); band uses exact replica act
  const float* gr = g + (size_t)row * 4096;
  u16* shr = s_hi + (size_t)row * 4096;
  u16* slr = s_lo + (size_t)row * 4096;
#pragma unroll
  for (int i = 0; i < 4; ++i) {
    const float4 gv = *(const float4*)&gr[i * 1024 + tid * 4];
    const float gvv[4] = { gv.x, gv.y, gv.z, gv.w };
    u16 oh[4], ol[4];
#pragma unroll
    for (int j = 0; j < 4; ++j) {
      const int f = i * 1024 + tid * 4 + j;
      float sval = 0.f;
      if (flag[f] == 2) {
        sval = sact[f] * gvv[j];
      } else if (flag[f] == 1) {
        const float zz = zreg[i * 4 + j];
        sval = (zz / (1.f + expf(-zz))) * gvv[j];
      }
      const u16 h = f2bf(sval);
      oh[j] = h;
      ol[j] = f2bf(sval - bf2f(h));
    }
    *(ushort4*)&shr[i * 1024 + tid * 4] = make_ushort4(oh[0], oh[1], oh[2], oh[3]);
    *(ushort4*)&slr[i * 1024 + tid * 4] = make_ushort4(ol[0], ol[1], ol[2], ol[3]);
  }
}

// ---------------- launch ----------------
extern "C" void kernel_launch(void* const* d_in, const int* in_sizes, int n_in,
                              void* d_out, int out_size, void* d_ws, size_t ws_size,
                              hipStream_t stream)
{
  const float* x  = (const float*)d_in[0];
  const float* W1 = (const float*)d_in[1];
  const float* W2 = (const float*)d_in[2];
  const float* Wo = (const float*)d_in[3];
  const int* kptr = (const int*)d_in[4];

  const int DM = 1024, DF = 4096;
  const int M = in_sizes[0] / DM;   // 8192 rows
  const size_t nX = (size_t)M * DM, nW = (size_t)DF * DM, nWo = (size_t)DM * DF;

  // fixed bf16 buffers
  char* w = (char*)d_ws;
  u16* x_hi  = (u16*)w;  w += nX * 2;
  u16* W1_hi = (u16*)w;  w += nW * 2;
  u16* W2_hi = (u16*)w;  w += nW * 2;
  u16* Wo_hi = (u16*)w;  w += nWo * 2;
  const size_t fixed_bytes = (size_t)(w - (char*)d_ws);

  // per-chunk activations: z(4) + g(4) + s_hi(2) + s_lo(2) = 12 B/elem
  int nch = 1;
  while (nch < 64) {
    const size_t per = (size_t)(M / nch) * DF * 12;
    if (fixed_bytes + per <= ws_size) break;
    nch *= 2;
  }
  const int Mc = M / nch;

  float* zbuf = (float*)w;
  float* gbuf = (float*)(w + (size_t)Mc * DF * 4);
  u16*   s_hi = (u16*)(w + (size_t)Mc * DF * 8);
  u16*   s_lo = (u16*)(w + (size_t)Mc * DF * 10);

  split1_kernel<<<dim3((int)((nX + 255) / 256)), 256, 0, stream>>>(x, x_hi, (int)nX);
  split1_kernel<<<dim3((int)((nW + 255) / 256)), 256, 0, stream>>>(W1, W1_hi, (int)nW);
  split1_kernel<<<dim3((int)((nW + 255) / 256)), 256, 0, stream>>>(W2, W2_hi, (int)nW);
  split1_kernel<<<dim3((int)((nWo + 255) / 256)), 256, 0, stream>>>(Wo, Wo_hi, (int)nWo);

  for (int ch = 0; ch < nch; ++ch) {
    const size_t ro = (size_t)ch * Mc;
    // z = x @ W1^T (1-pass bf16; band machinery absorbs the error)
    gemm_bt<64><<<dim3(DF / 128, Mc / 128), 256, 0, stream>>>(
        x_hi + ro * DM, W1_hi, zbuf, DF, DM);
    // gate = x @ W2^T (1-pass bf16)
    gemm_bt<64><<<dim3(DF / 128, Mc / 128), 256, 0, stream>>>(
        x_hi + ro * DM, W2_hi, gbuf, DF, DM);
    // top-k: bisection + wide band + replica keys; writes s hi/lo
    select5_kernel<<<dim3(Mc), 256, 0, stream>>>(
        zbuf, gbuf, x + ro * DM, W1, s_hi, s_lo, kptr);
    // out = [s_hi|s_lo] @ [Wo|Wo]^T (2-segment split-A, fp32-faithful s)
    gemm2s_kernel<64><<<dim3(DM / 128, Mc / 128), 256, 0, stream>>>(
        s_hi, s_lo, Wo_hi, (float*)d_out + ro * DM, DM, DF);
  }
}

// Round 10
// 1002.993 us; speedup vs baseline: 1.0278x; 1.0278x over previous
//
#include <hip/hip_runtime.h>
#include <stdint.h>

#define DEV __device__ __forceinline__

using f32x4  = __attribute__((ext_vector_type(4))) float;
using bf16x8 = __attribute__((ext_vector_type(8))) short;
typedef unsigned short u16;
typedef unsigned int   u32;

typedef const __attribute__((address_space(1))) void* gptr_t;
typedef __attribute__((address_space(3))) void*       lptr_t;

DEV u16 f2bf(float f) {               // RTNE float -> bf16 bits
  union { float f; u32 u; } v; v.f = f;
  u32 lsb = (v.u >> 16) & 1u;
  v.u += 0x7fffu + lsb;
  return (u16)(v.u >> 16);
}
DEV float bf2f(u16 h) {
  union { u32 u; float f; } v; v.u = ((u32)h) << 16;
  return v.f;
}
DEV void async16(void* lds, const void* g) {
  __builtin_amdgcn_global_load_lds((gptr_t)(uintptr_t)g,
                                   (lptr_t)(u32)(uintptr_t)lds, 16, 0, 0);
}
// monotone float->uint key (ascending order preserved); bijective
DEV u32 fkey(float v) {
  u32 u = __float_as_uint(v);
  return u ^ ((u & 0x80000000u) ? 0xFFFFFFFFu : 0x80000000u);
}
DEV float unfkey(u32 key) {
  const u32 ub = (key & 0x80000000u) ? (key ^ 0x80000000u) : ~key;
  return __uint_as_float(ub);
}

// bit-exact replica of np.einsum fp32 inner dot (sum_of_products_contig_outstride0_two,
// SSE-128 baseline, no FMA): 4 lanes (j === l mod 4); per 16-block reversed chain;
// combine (v0+v1)+(v2+v3) via SSE3 hadd. 1024 = 64 blocks, no tail. [R6-validated]
DEV float replica_dot(const float* __restrict__ xr, const float* __restrict__ wr) {
  float v0 = 0.f, v1 = 0.f, v2 = 0.f, v3 = 0.f;
  for (int j = 0; j < 1024; j += 16) {
    float t0 = __fadd_rn(__fmul_rn(xr[j + 12], wr[j + 12]), v0);
    float t1 = __fadd_rn(__fmul_rn(xr[j + 13], wr[j + 13]), v1);
    float t2 = __fadd_rn(__fmul_rn(xr[j + 14], wr[j + 14]), v2);
    float t3 = __fadd_rn(__fmul_rn(xr[j + 15], wr[j + 15]), v3);
    t0 = __fadd_rn(__fmul_rn(xr[j + 8],  wr[j + 8]),  t0);
    t1 = __fadd_rn(__fmul_rn(xr[j + 9],  wr[j + 9]),  t1);
    t2 = __fadd_rn(__fmul_rn(xr[j + 10], wr[j + 10]), t2);
    t3 = __fadd_rn(__fmul_rn(xr[j + 11], wr[j + 11]), t3);
    t0 = __fadd_rn(__fmul_rn(xr[j + 4],  wr[j + 4]),  t0);
    t1 = __fadd_rn(__fmul_rn(xr[j + 5],  wr[j + 5]),  t1);
    t2 = __fadd_rn(__fmul_rn(xr[j + 6],  wr[j + 6]),  t2);
    t3 = __fadd_rn(__fmul_rn(xr[j + 7],  wr[j + 7]),  t3);
    v0 = __fadd_rn(__fmul_rn(xr[j + 0],  wr[j + 0]),  t0);
    v1 = __fadd_rn(__fmul_rn(xr[j + 1],  wr[j + 1]),  t1);
    v2 = __fadd_rn(__fmul_rn(xr[j + 2],  wr[j + 2]),  t2);
    v3 = __fadd_rn(__fmul_rn(xr[j + 3],  wr[j + 3]),  t3);
  }
  return __fadd_rn(__fadd_rn(v0, v1), __fadd_rn(v2, v3));
}

// ---------------- split kernel: fp32 -> bf16 ----------------
__global__ __launch_bounds__(256) void split1_kernel(const float* __restrict__ src,
                                                     u16* __restrict__ hi, int n) {
  int i = blockIdx.x * 256 + threadIdx.x;
  if (i >= n) return;
  hi[i] = f2bf(src[i]);
}

// XCD-aware block swizzle (nwg % 8 == 0 for all our grids)
DEV void swz_block(int& bx, int& by) {
  const int gx = gridDim.x, nwg = gx * gridDim.y;
  const int lid = by * gx + bx;
  const int cpx = nwg >> 3;
  const int swz = (lid & 7) * cpx + (lid >> 3);
  bx = swz % gx; by = swz / gx;
}

// ------- GEMM 1-pass bf16: C = A*B^T fp32 out (fused z|gate) -------
template<int BK>
__global__ __launch_bounds__(256) void gemm_bt(
    const u16* __restrict__ A, const u16* __restrict__ B,
    float* __restrict__ C, int N, int K)
{
  constexpr int TILE = 128 * BK;
  __shared__ u16 smem[2 * TILE];
  u16* sA = smem;
  u16* sB = smem + TILE;

  const int tid  = threadIdx.x;
  const int lane = tid & 63;
  const int wave = tid >> 6;
  const int wr = wave >> 1, wc = wave & 1;
  int bx = blockIdx.x, by = blockIdx.y;
  swz_block(bx, by);
  const int m0 = by * 128, n0 = bx * 128;

  f32x4 acc[4][4] = {};
  constexpr int SPR   = BK / 8;
  constexpr int ITERS = (128 * SPR) / 256;

  for (int k0 = 0; k0 < K; k0 += BK) {
#pragma unroll
    for (int i = 0; i < ITERS; ++i) {
      const int slot = i * 256 + tid;
      const int r = slot / SPR, cc = slot % SPR;
      const int uni = (i * 256 + wave * 64) * 8;
      async16(sA + uni, A + (size_t)(m0 + r) * K + k0 + cc * 8);
      async16(sB + uni, B + (size_t)(n0 + r) * K + k0 + cc * 8);
    }
    __syncthreads();

#pragma unroll
    for (int ks = 0; ks < BK / 32; ++ks) {
      const int kb = ks * 32 + (lane >> 4) * 8;
      bf16x8 a[4], b[4];
#pragma unroll
      for (int i = 0; i < 4; ++i) {
        a[i] = *(const bf16x8*)&sA[(wr * 64 + i * 16 + (lane & 15)) * BK + kb];
        b[i] = *(const bf16x8*)&sB[(wc * 64 + i * 16 + (lane & 15)) * BK + kb];
      }
#pragma unroll
      for (int mi = 0; mi < 4; ++mi)
#pragma unroll
        for (int ni = 0; ni < 4; ++ni)
          acc[mi][ni] = __builtin_amdgcn_mfma_f32_16x16x32_bf16(a[mi], b[ni], acc[mi][ni], 0, 0, 0);
    }
    __syncthreads();
  }

#pragma unroll
  for (int mi = 0; mi < 4; ++mi) {
    const int rbase = m0 + wr * 64 + mi * 16 + (lane >> 4) * 4;
#pragma unroll
    for (int ni = 0; ni < 4; ++ni) {
      const int col = n0 + wc * 64 + ni * 16 + (lane & 15);
#pragma unroll
      for (int r2 = 0; r2 < 4; ++r2)
        C[(size_t)(rbase + r2) * N + col] = acc[mi][ni][r2];
    }
  }
}

// ------- down GEMM, 2-segment split-A: C = [Ahi|Alo] . [B|B] over K'=2K -------
template<int BK>
__global__ __launch_bounds__(256) void gemm2s_kernel(
    const u16* __restrict__ Ahi, const u16* __restrict__ Alo,
    const u16* __restrict__ B, float* __restrict__ C, int N, int K)
{
  constexpr int TILE = 128 * BK;
  __shared__ u16 smem[2 * TILE];
  u16* sA = smem;
  u16* sB = smem + TILE;

  const int tid  = threadIdx.x;
  const int lane = tid & 63;
  const int wave = tid >> 6;
  const int wr = wave >> 1, wc = wave & 1;
  int bx = blockIdx.x, by = blockIdx.y;
  swz_block(bx, by);
  const int m0 = by * 128, n0 = bx * 128;

  f32x4 acc[4][4] = {};
  constexpr int SPR   = BK / 8;
  constexpr int ITERS = (128 * SPR) / 256;

  for (int kt = 0; kt < 2 * K; kt += BK) {
    const int seg = (kt >= K) ? 1 : 0;
    const int kl  = kt - seg * K;
    const u16* __restrict__ Asrc = seg ? Alo : Ahi;
#pragma unroll
    for (int i = 0; i < ITERS; ++i) {
      const int slot = i * 256 + tid;
      const int r = slot / SPR, cc = slot % SPR;
      const int uni = (i * 256 + wave * 64) * 8;
      async16(sA + uni, Asrc + (size_t)(m0 + r) * K + kl + cc * 8);
      async16(sB + uni, B + (size_t)(n0 + r) * K + kl + cc * 8);
    }
    __syncthreads();

#pragma unroll
    for (int ks = 0; ks < BK / 32; ++ks) {
      const int kb = ks * 32 + (lane >> 4) * 8;
      bf16x8 a[4], b[4];
#pragma unroll
      for (int i = 0; i < 4; ++i) {
        a[i] = *(const bf16x8*)&sA[(wr * 64 + i * 16 + (lane & 15)) * BK + kb];
        b[i] = *(const bf16x8*)&sB[(wc * 64 + i * 16 + (lane & 15)) * BK + kb];
      }
#pragma unroll
      for (int mi = 0; mi < 4; ++mi)
#pragma unroll
        for (int ni = 0; ni < 4; ++ni)
          acc[mi][ni] = __builtin_amdgcn_mfma_f32_16x16x32_bf16(a[mi], b[ni], acc[mi][ni], 0, 0, 0);
    }
    __syncthreads();
  }

#pragma unroll
  for (int mi = 0; mi < 4; ++mi) {
    const int rbase = m0 + wr * 64 + mi * 16 + (lane >> 4) * 4;
#pragma unroll
    for (int ni = 0; ni < 4; ++ni) {
      const int col = n0 + wc * 64 + ni * 16 + (lane & 15);
#pragma unroll
      for (int r2 = 0; r2 < 4; ++r2)
        C[(size_t)(rbase + r2) * N + col] = acc[mi][ni][r2];
    }
  }
}

// ---------------- per-row top-k select (LDS-staged, no per-thread arrays) ----------------
// Semantics identical to R9 select5 (validated): 20-step bisection on 1-pass-GEMM z
// (float-domain compares, fkey-monotone-equivalent); D = {z-tau > 1.5e-2} definite;
// band |z-tau| <= 1.5e-2 re-ranked by bit-exact numpy-replica fp32 act keys, stable
// index tie-break, top (k-D) taken. Writes s = act*gate as bf16 hi/lo pair.
__global__ __launch_bounds__(256) void select6_kernel(
    const float* __restrict__ zg, const float* __restrict__ xin,
    const float* __restrict__ W1,
    u16* __restrict__ s_hi, u16* __restrict__ s_lo,
    const int* __restrict__ kptr)
{
  const int row = blockIdx.x, tid = threadIdx.x;
  const int lane = tid & 63, wave = tid >> 6;
  const int k = *kptr;

  __shared__ float zs[4096];            // 16 KB, z row (band entries later hold act)
  __shared__ float xrow[1024];          // 4 KB
  __shared__ unsigned char flag[4096];  // 4 KB
  __shared__ int wsum[4];
  __shared__ int s_nb;
  __shared__ int band_idx[256];
  __shared__ u32 band_key[256];
  __shared__ float band_act[256];

  const float* zrow = zg + (size_t)row * 8192;
  const float* grow = zrow + 4096;

  // stage z + x, clear flags
#pragma unroll
  for (int q = 0; q < 4; ++q)
    *(float4*)&zs[q * 1024 + tid * 4] = *(const float4*)&zrow[q * 1024 + tid * 4];
  *(float4*)&xrow[tid * 4] = *(const float4*)&xin[(size_t)row * 1024 + tid * 4];
  *(u32*)&flag[tid * 4] = 0u;
  *(u32*)&flag[1024 + tid * 4] = 0u;
  *(u32*)&flag[2048 + tid * 4] = 0u;
  *(u32*)&flag[3072 + tid * 4] = 0u;
  if (tid == 0) s_nb = 0;
  __syncthreads();

  // 20-step MSB bisection for ~kth largest (float-domain compares; quantum 2.4e-4)
  u32 prefix = 0;
  for (int step = 0; step < 20; ++step) {
    const u32 c = prefix | (1u << (31 - step));
    const float zc = unfkey(c);
    int cnt = 0;
#pragma unroll
    for (int q = 0; q < 4; ++q) {
      const float4 v = *(const float4*)&zs[q * 1024 + tid * 4];
      cnt += (v.x >= zc) + (v.y >= zc) + (v.z >= zc) + (v.w >= zc);
    }
    for (int off = 32; off; off >>= 1) cnt += __shfl_xor(cnt, off);
    if (lane == 0) wsum[wave] = cnt;
    __syncthreads();
    const int tot = wsum[0] + wsum[1] + wsum[2] + wsum[3];
    if (tot >= k) prefix = c;
    __syncthreads();
  }
  const float tau = unfkey(prefix);
  const float BANDW = 1.5e-2f;
  const float thi = tau + BANDW, tlo = tau - BANDW;

  // classify: D flags + band gather + D count
  int cntD = 0;
#pragma unroll
  for (int q = 0; q < 4; ++q) {
    const float4 v = *(const float4*)&zs[q * 1024 + tid * 4];
    const float vv[4] = { v.x, v.y, v.z, v.w };
#pragma unroll
    for (int j = 0; j < 4; ++j) {
      const int f = q * 1024 + tid * 4 + j;
      if (vv[j] > thi) { flag[f] = 1; ++cntD; }
      else if (vv[j] >= tlo) {
        const int p = atomicAdd(&s_nb, 1);
        if (p < 256) band_idx[p] = f;
      }
    }
  }
  for (int off = 32; off; off >>= 1) cntD += __shfl_xor(cntD, off);
  if (lane == 0) wsum[wave] = cntD;
  __syncthreads();
  const int D = wsum[0] + wsum[1] + wsum[2] + wsum[3];
  const int nb = (s_nb < 256) ? s_nb : 256;
  const int need = k - D;

  // exact numpy-replica act keys for band channels
  for (int i = tid; i < nb; i += 256) {
    const int f = band_idx[i];
    const float zrep = replica_dot(xrow, W1 + (size_t)f * 1024);
    const double zd = (double)zrep;
    const float a = (float)(zd / (1.0 + exp(-zd)));
    band_act[i] = a;
    band_key[i] = fkey(a);
  }
  __syncthreads();

  // stable rank (exact key desc, index asc); selected band entries: flag=2, zs <- act
  for (int i = tid; i < nb; i += 256) {
    const u32 ki = band_key[i];
    const int fi = band_idx[i];
    int rank = 0;
    for (int j = 0; j < nb; ++j) {
      const u32 kj = band_key[j];
      rank += (kj > ki || (kj == ki && band_idx[j] < fi)) ? 1 : 0;
    }
    if (rank < need) { flag[fi] = 2; zs[fi] = band_act[i]; }
  }
  __syncthreads();

  // write s = act * gate (bf16 hi/lo pair)
  u16* shr = s_hi + (size_t)row * 4096;
  u16* slr = s_lo + (size_t)row * 4096;
#pragma unroll
  for (int q = 0; q < 4; ++q) {
    const int f0 = q * 1024 + tid * 4;
    const float4 gv = *(const float4*)&grow[f0];
    const float4 zv = *(const float4*)&zs[f0];
    const float gvv[4] = { gv.x, gv.y, gv.z, gv.w };
    const float zvv[4] = { zv.x, zv.y, zv.z, zv.w };
    const u32 fl = *(const u32*)&flag[f0];
    u16 oh[4], ol[4];
#pragma unroll
    for (int j = 0; j < 4; ++j) {
      const u32 fj = (fl >> (8 * j)) & 0xFF;
      float sval = 0.f;
      if (fj == 2) {
        sval = zvv[j] * gvv[j];                       // zs holds exact replica act
      } else if (fj == 1) {
        const float zz = zvv[j];
        sval = (zz / (1.f + expf(-zz))) * gvv[j];
      }
      const u16 h = f2bf(sval);
      oh[j] = h;
      ol[j] = f2bf(sval - bf2f(h));
    }
    *(ushort4*)&shr[f0] = make_ushort4(oh[0], oh[1], oh[2], oh[3]);
    *(ushort4*)&slr[f0] = make_ushort4(ol[0], ol[1], ol[2], ol[3]);
  }
}

// ---------------- launch ----------------
extern "C" void kernel_launch(void* const* d_in, const int* in_sizes, int n_in,
                              void* d_out, int out_size, void* d_ws, size_t ws_size,
                              hipStream_t stream)
{
  const float* x  = (const float*)d_in[0];
  const float* W1 = (const float*)d_in[1];
  const float* W2 = (const float*)d_in[2];
  const float* Wo = (const float*)d_in[3];
  const int* kptr = (const int*)d_in[4];

  const int DM = 1024, DF = 4096;
  const int M = in_sizes[0] / DM;   // 8192 rows
  const size_t nX = (size_t)M * DM, nW = (size_t)DF * DM, nWo = (size_t)DM * DF;

  // fixed bf16 buffers: x, [W1;W2] concat, Wo
  char* w = (char*)d_ws;
  u16* x_hi   = (u16*)w;  w += nX * 2;
  u16* w12_hi = (u16*)w;  w += 2 * nW * 2;
  u16* wo_hi  = (u16*)w;  w += nWo * 2;
  const size_t fixed_bytes = (size_t)(w - (char*)d_ws);

  // per-chunk: zg (8 B/DF-elem) + s pair (4 B/DF-elem) = 12 B/elem
  int nch = 1;
  while (nch < 64) {
    const size_t per = (size_t)(M / nch) * DF * 12;
    if (fixed_bytes + per <= ws_size) break;
    nch *= 2;
  }
  const int Mc = M / nch;

  float* zgbuf = (float*)w;
  u16*   s_hi  = (u16*)(w + (size_t)Mc * DF * 8);
  u16*   s_lo  = (u16*)(w + (size_t)Mc * DF * 10);

  split1_kernel<<<dim3((int)((nX + 255) / 256)), 256, 0, stream>>>(x, x_hi, (int)nX);
  split1_kernel<<<dim3((int)((nW + 255) / 256)), 256, 0, stream>>>(W1, w12_hi, (int)nW);
  split1_kernel<<<dim3((int)((nW + 255) / 256)), 256, 0, stream>>>(W2, w12_hi + nW, (int)nW);
  split1_kernel<<<dim3((int)((nWo + 255) / 256)), 256, 0, stream>>>(Wo, wo_hi, (int)nWo);

  for (int ch = 0; ch < nch; ++ch) {
    const size_t ro = (size_t)ch * Mc;
    // [z|gate] = x @ [W1;W2]^T  (one fused 1-pass bf16 GEMM, N=8192)
    gemm_bt<64><<<dim3(2 * DF / 128, Mc / 128), 256, 0, stream>>>(
        x_hi + ro * DM, w12_hi, zgbuf, 2 * DF, DM);
    // top-k: bisection + wide band + replica keys; writes s hi/lo
    select6_kernel<<<dim3(Mc), 256, 0, stream>>>(
        zgbuf, x + ro * DM, W1, s_hi, s_lo, kptr);
    // out = [s_hi|s_lo] @ [Wo|Wo]^T (2-segment split-A, fp32-faithful s)
    gemm2s_kernel<64><<<dim3(DM / 128, Mc / 128), 256, 0, stream>>>(
        s_hi, s_lo, wo_hi, (float*)d_out + ro * DM, DM, DF);
  }
}

// Round 11
// 763.494 us; speedup vs baseline: 1.3502x; 1.3137x over previous
//
#include <hip/hip_runtime.h>
#include <stdint.h>

#define DEV __device__ __forceinline__

using f32x4  = __attribute__((ext_vector_type(4))) float;
using bf16x8 = __attribute__((ext_vector_type(8))) short;
typedef unsigned short u16;
typedef unsigned int   u32;

typedef const __attribute__((address_space(1))) void* gptr_t;
typedef __attribute__((address_space(3))) void*       lptr_t;

DEV u16 f2bf(float f) {               // RTNE float -> bf16 bits
  union { float f; u32 u; } v; v.f = f;
  u32 lsb = (v.u >> 16) & 1u;
  v.u += 0x7fffu + lsb;
  return (u16)(v.u >> 16);
}
DEV float bf2f(u16 h) {
  union { u32 u; float f; } v; v.u = ((u32)h) << 16;
  return v.f;
}
DEV void async16(void* lds, const void* g) {
  __builtin_amdgcn_global_load_lds((gptr_t)(uintptr_t)g,
                                   (lptr_t)(u32)(uintptr_t)lds, 16, 0, 0);
}
// monotone float->uint key (ascending order preserved); bijective
DEV u32 fkey(float v) {
  u32 u = __float_as_uint(v);
  return u ^ ((u & 0x80000000u) ? 0xFFFFFFFFu : 0x80000000u);
}
DEV float unfkey(u32 key) {
  const u32 ub = (key & 0x80000000u) ? (key ^ 0x80000000u) : ~key;
  return __uint_as_float(ub);
}

// ---------------- split kernel: fp32 -> bf16 ----------------
__global__ __launch_bounds__(256) void split1_kernel(const float* __restrict__ src,
                                                     u16* __restrict__ hi, int n) {
  int i = blockIdx.x * 256 + threadIdx.x;
  if (i >= n) return;
  hi[i] = f2bf(src[i]);
}

// XCD-aware block swizzle (nwg % 8 == 0 for all our grids)
DEV void swz_block(int& bx, int& by) {
  const int gx = gridDim.x, nwg = gx * gridDim.y;
  const int lid = by * gx + bx;
  const int cpx = nwg >> 3;
  const int swz = (lid & 7) * cpx + (lid >> 3);
  bx = swz % gx; by = swz / gx;
}

// ------- GEMM 1-pass bf16: C = A*B^T fp32 out (fused z|gate; down-proj) -------
template<int BK>
__global__ __launch_bounds__(256) void gemm_bt(
    const u16* __restrict__ A, const u16* __restrict__ B,
    float* __restrict__ C, int N, int K)
{
  constexpr int TILE = 128 * BK;
  __shared__ u16 smem[2 * TILE];
  u16* sA = smem;
  u16* sB = smem + TILE;

  const int tid  = threadIdx.x;
  const int lane = tid & 63;
  const int wave = tid >> 6;
  const int wr = wave >> 1, wc = wave & 1;
  int bx = blockIdx.x, by = blockIdx.y;
  swz_block(bx, by);
  const int m0 = by * 128, n0 = bx * 128;

  f32x4 acc[4][4] = {};
  constexpr int SPR   = BK / 8;
  constexpr int ITERS = (128 * SPR) / 256;

  for (int k0 = 0; k0 < K; k0 += BK) {
#pragma unroll
    for (int i = 0; i < ITERS; ++i) {
      const int slot = i * 256 + tid;
      const int r = slot / SPR, cc = slot % SPR;
      const int uni = (i * 256 + wave * 64) * 8;
      async16(sA + uni, A + (size_t)(m0 + r) * K + k0 + cc * 8);
      async16(sB + uni, B + (size_t)(n0 + r) * K + k0 + cc * 8);
    }
    __syncthreads();

#pragma unroll
    for (int ks = 0; ks < BK / 32; ++ks) {
      const int kb = ks * 32 + (lane >> 4) * 8;
      bf16x8 a[4], b[4];
#pragma unroll
      for (int i = 0; i < 4; ++i) {
        a[i] = *(const bf16x8*)&sA[(wr * 64 + i * 16 + (lane & 15)) * BK + kb];
        b[i] = *(const bf16x8*)&sB[(wc * 64 + i * 16 + (lane & 15)) * BK + kb];
      }
#pragma unroll
      for (int mi = 0; mi < 4; ++mi)
#pragma unroll
        for (int ni = 0; ni < 4; ++ni)
          acc[mi][ni] = __builtin_amdgcn_mfma_f32_16x16x32_bf16(a[mi], b[ni], acc[mi][ni], 0, 0, 0);
    }
    __syncthreads();
  }

#pragma unroll
  for (int mi = 0; mi < 4; ++mi) {
    const int rbase = m0 + wr * 64 + mi * 16 + (lane >> 4) * 4;
#pragma unroll
    for (int ni = 0; ni < 4; ++ni) {
      const int col = n0 + wc * 64 + ni * 16 + (lane & 15);
#pragma unroll
      for (int r2 = 0; r2 < 4; ++r2)
        C[(size_t)(rbase + r2) * N + col] = acc[mi][ni][r2];
    }
  }
}

// ---------------- per-row top-k select (register z, 4-wide replica dots) ------------
// Semantics identical to R9/R10 (validated): 20-step bisection on 1-pass-GEMM z;
// D = {z-tau > 1.5e-2} definite; band |z-tau| <= 1.5e-2 re-ranked by bit-exact
// numpy-replica fp32 act keys (SSE lanes v0..v3 = one HW lane each, exact hadd
// combine), stable index tie-break, top (k-D) taken. Writes s = act*gate (bf16).
__global__ __launch_bounds__(256) void select7_kernel(
    const float* __restrict__ zg, const float* __restrict__ xin,
    const float* __restrict__ W1,
    u16* __restrict__ sbuf, const int* __restrict__ kptr)
{
  const int row = blockIdx.x, tid = threadIdx.x;
  const int lane = tid & 63, wave = tid >> 6;
  const int k = *kptr;

  __shared__ float xrow[1024];          // 4 KB
  __shared__ float sact[4096];          // 16 KB (band act by channel; only band-selected read)
  __shared__ unsigned char flag[4096];  // 4 KB
  __shared__ int wsum[4];
  __shared__ int s_nb;
  __shared__ int band_idx[256];
  __shared__ u32 band_key[256];
  __shared__ float band_act[256];

  const float* zrow = zg + (size_t)row * 8192;
  const float* grow = zrow + 4096;

  // z row -> registers (static indexing only); x -> LDS; clear flags
  float zreg[16];
#pragma unroll
  for (int q = 0; q < 4; ++q) {
    const float4 v = *(const float4*)&zrow[q * 1024 + tid * 4];
    zreg[q * 4 + 0] = v.x; zreg[q * 4 + 1] = v.y;
    zreg[q * 4 + 2] = v.z; zreg[q * 4 + 3] = v.w;
  }
  *(float4*)&xrow[tid * 4] = *(const float4*)&xin[(size_t)row * 1024 + tid * 4];
  *(u32*)&flag[tid * 4] = 0u;
  *(u32*)&flag[1024 + tid * 4] = 0u;
  *(u32*)&flag[2048 + tid * 4] = 0u;
  *(u32*)&flag[3072 + tid * 4] = 0u;
  if (tid == 0) s_nb = 0;
  __syncthreads();

  // 20-step MSB bisection for ~kth largest (register compares; quantum 2.4e-4)
  u32 prefix = 0;
  for (int step = 0; step < 20; ++step) {
    const u32 c = prefix | (1u << (31 - step));
    const float zc = unfkey(c);
    int cnt = 0;
#pragma unroll
    for (int i = 0; i < 16; ++i) cnt += (zreg[i] >= zc) ? 1 : 0;
    for (int off = 32; off; off >>= 1) cnt += __shfl_xor(cnt, off);
    if (lane == 0) wsum[wave] = cnt;
    __syncthreads();
    const int tot = wsum[0] + wsum[1] + wsum[2] + wsum[3];
    if (tot >= k) prefix = c;
    __syncthreads();
  }
  const float tau = unfkey(prefix);
  const float BANDW = 1.5e-2f;
  const float thi = tau + BANDW, tlo = tau - BANDW;

  // classify: D flags + band gather + D count
  int cntD = 0;
#pragma unroll
  for (int q = 0; q < 4; ++q)
#pragma unroll
    for (int j = 0; j < 4; ++j) {
      const int f = q * 1024 + tid * 4 + j;
      const float zv = zreg[q * 4 + j];
      if (zv > thi) { flag[f] = 1; ++cntD; }
      else if (zv >= tlo) {
        const int p = atomicAdd(&s_nb, 1);
        if (p < 256) band_idx[p] = f;
      }
    }
  for (int off = 32; off; off >>= 1) cntD += __shfl_xor(cntD, off);
  if (lane == 0) wsum[wave] = cntD;
  __syncthreads();
  const int D = wsum[0] + wsum[1] + wsum[2] + wsum[3];
  const int nb = (s_nb < 256) ? s_nb : 256;
  const int need = k - D;

  // 4-wide numpy-replica dots: group g = tid>>2 handles band entry i; HW lane
  // l = tid&3 computes SSE-lane chain v_l; exact hadd combine (v0+v1)+(v2+v3).
  {
    const int gi = tid >> 2, l = tid & 3;
    const int wl = lane & ~3;           // group base within wave (groups never straddle)
    for (int i = gi; i < nb; i += 64) {
      const int f = band_idx[i];
      const float* wr = W1 + (size_t)f * 1024;
      float v = 0.f;
#pragma unroll 8
      for (int b = 0; b < 1024; b += 16) {
        float t = __fadd_rn(__fmul_rn(xrow[b + 12 + l], wr[b + 12 + l]), v);
        t = __fadd_rn(__fmul_rn(xrow[b + 8 + l],  wr[b + 8 + l]),  t);
        t = __fadd_rn(__fmul_rn(xrow[b + 4 + l],  wr[b + 4 + l]),  t);
        v = __fadd_rn(__fmul_rn(xrow[b + 0 + l],  wr[b + 0 + l]),  t);
      }
      const float c0 = __shfl(v, wl + 0);
      const float c1 = __shfl(v, wl + 1);
      const float c2 = __shfl(v, wl + 2);
      const float c3 = __shfl(v, wl + 3);
      if (l == 0) {
        const float zrep = __fadd_rn(__fadd_rn(c0, c1), __fadd_rn(c2, c3));
        const double zd = (double)zrep;
        const float a = (float)(zd / (1.0 + exp(-zd)));
        band_act[i] = a;
        band_key[i] = fkey(a);
      }
    }
  }
  __syncthreads();

  // stable rank (exact key desc, index asc); selected band: flag=2, sact <- act
  for (int i = tid; i < nb; i += 256) {
    const u32 ki = band_key[i];
    const int fi = band_idx[i];
    int rank = 0;
    for (int j = 0; j < nb; ++j) {
      const u32 kj = band_key[j];
      rank += (kj > ki || (kj == ki && band_idx[j] < fi)) ? 1 : 0;
    }
    if (rank < need) { flag[fi] = 2; sact[fi] = band_act[i]; }
  }
  __syncthreads();

  // write s = act * gate (bf16)
  u16* srow = sbuf + (size_t)row * 4096;
#pragma unroll
  for (int q = 0; q < 4; ++q) {
    const int f0 = q * 1024 + tid * 4;
    const float4 gv = *(const float4*)&grow[f0];
    const float gvv[4] = { gv.x, gv.y, gv.z, gv.w };
    const u32 fl = *(const u32*)&flag[f0];
    u16 out[4];
#pragma unroll
    for (int j = 0; j < 4; ++j) {
      const u32 fj = (fl >> (8 * j)) & 0xFF;
      float sval = 0.f;
      if (fj == 2) {
        sval = sact[f0 + j] * gvv[j];                 // exact replica act
      } else if (fj == 1) {
        const float zz = zreg[q * 4 + j];
        sval = (zz / (1.f + expf(-zz))) * gvv[j];
      }
      out[j] = f2bf(sval);
    }
    *(ushort4*)&srow[f0] = make_ushort4(out[0], out[1], out[2], out[3]);
  }
}

// ---------------- launch ----------------
extern "C" void kernel_launch(void* const* d_in, const int* in_sizes, int n_in,
                              void* d_out, int out_size, void* d_ws, size_t ws_size,
                              hipStream_t stream)
{
  const float* x  = (const float*)d_in[0];
  const float* W1 = (const float*)d_in[1];
  const float* W2 = (const float*)d_in[2];
  const float* Wo = (const float*)d_in[3];
  const int* kptr = (const int*)d_in[4];

  const int DM = 1024, DF = 4096;
  const int M = in_sizes[0] / DM;   // 8192 rows
  const size_t nX = (size_t)M * DM, nW = (size_t)DF * DM, nWo = (size_t)DM * DF;

  // fixed bf16 buffers: x, [W1;W2] concat, Wo
  char* w = (char*)d_ws;
  u16* x_hi   = (u16*)w;  w += nX * 2;
  u16* w12_hi = (u16*)w;  w += 2 * nW * 2;
  u16* wo_hi  = (u16*)w;  w += nWo * 2;
  const size_t fixed_bytes = (size_t)(w - (char*)d_ws);

  // per-chunk: zg (8 B/DF-elem) + s (2 B/DF-elem) = 10 B/elem
  int nch = 1;
  while (nch < 64) {
    const size_t per = (size_t)(M / nch) * DF * 10;
    if (fixed_bytes + per <= ws_size) break;
    nch *= 2;
  }
  const int Mc = M / nch;

  float* zgbuf = (float*)w;
  u16*   sbuf  = (u16*)(w + (size_t)Mc * DF * 8);

  split1_kernel<<<dim3((int)((nX + 255) / 256)), 256, 0, stream>>>(x, x_hi, (int)nX);
  split1_kernel<<<dim3((int)((nW + 255) / 256)), 256, 0, stream>>>(W1, w12_hi, (int)nW);
  split1_kernel<<<dim3((int)((nW + 255) / 256)), 256, 0, stream>>>(W2, w12_hi + nW, (int)nW);
  split1_kernel<<<dim3((int)((nWo + 255) / 256)), 256, 0, stream>>>(Wo, wo_hi, (int)nWo);

  for (int ch = 0; ch < nch; ++ch) {
    const size_t ro = (size_t)ch * Mc;
    // [z|gate] = x @ [W1;W2]^T  (one fused 1-pass bf16 GEMM, N=8192)
    gemm_bt<64><<<dim3(2 * DF / 128, Mc / 128), 256, 0, stream>>>(
        x_hi + ro * DM, w12_hi, zgbuf, 2 * DF, DM);
    // top-k: bisection + wide band + 4-wide replica keys; writes s (bf16)
    select7_kernel<<<dim3(Mc), 256, 0, stream>>>(
        zgbuf, x + ro * DM, W1, sbuf, kptr);
    // out = s @ Wo^T (1-pass bf16)
    gemm_bt<64><<<dim3(DM / 128, Mc / 128), 256, 0, stream>>>(
        sbuf, wo_hi, (float*)d_out + ro * DM, DM, DF);
  }
}

// Round 13
// 694.256 us; speedup vs baseline: 1.4849x; 1.0997x over previous
//
#include <hip/hip_runtime.h>
#include <stdint.h>

#define DEV __device__ __forceinline__

using f32x4  = __attribute__((ext_vector_type(4))) float;
using bf16x8 = __attribute__((ext_vector_type(8))) short;
typedef unsigned short u16;
typedef unsigned int   u32;

typedef const __attribute__((address_space(1))) void* gptr_t;
typedef __attribute__((address_space(3))) void*       lptr_t;

DEV u16 f2bf(float f) {               // RTNE float -> bf16 bits
  union { float f; u32 u; } v; v.f = f;
  u32 lsb = (v.u >> 16) & 1u;
  v.u += 0x7fffu + lsb;
  return (u16)(v.u >> 16);
}
DEV float bf2f(u16 h) {
  union { u32 u; float f; } v; v.u = ((u32)h) << 16;
  return v.f;
}
DEV void async16(void* lds, const void* g) {
  __builtin_amdgcn_global_load_lds((gptr_t)(uintptr_t)g,
                                   (lptr_t)(u32)(uintptr_t)lds, 16, 0, 0);
}
// monotone float->uint key (ascending order preserved); bijective
DEV u32 fkey(float v) {
  u32 u = __float_as_uint(v);
  return u ^ ((u & 0x80000000u) ? 0xFFFFFFFFu : 0x80000000u);
}
DEV float unfkey(u32 key) {
  const u32 ub = (key & 0x80000000u) ? (key ^ 0x80000000u) : ~key;
  return __uint_as_float(ub);
}

// ---------------- split kernel: fp32 -> bf16 ----------------
__global__ __launch_bounds__(256) void split1_kernel(const float* __restrict__ src,
                                                     u16* __restrict__ hi, int n) {
  int i = blockIdx.x * 256 + threadIdx.x;
  if (i >= n) return;
  hi[i] = f2bf(src[i]);
}

// XCD-aware block swizzle (nwg % 8 == 0 for all our grids)
DEV void swz_block(int& bx, int& by) {
  const int gx = gridDim.x, nwg = gx * gridDim.y;
  const int lid = by * gx + bx;
  const int cpx = nwg >> 3;
  const int swz = (lid & 7) * cpx + (lid >> 3);
  bx = swz % gx; by = swz / gx;
}

// ======= 8-phase 256x256 GEMM (T2+T3+T4+T5), C = A*B^T fp32 out =======
// 512 threads = 8 waves (2M x 4N); per-wave C 128x64 (8x4 16x16x32 frags).
// LDS 128 KB: [buf2][A/B][half2][128x64 bf16], swizzle cs ^= (row&7) applied to
// the GLOBAL source (gload_lds dest linear) and to ds_read addresses.
// RACE-FIXED schedule (R12 post-mortem): read-completion table says buf0.A free
// after p2, buf0.B free after p3, buf1.* free after prev p7. Stages:
//   p0: A(2i+1)->buf1 (h0+h1)   p1: B(2i+1)->buf1 (h0+h1)
//   p4: A(2i+2)->buf0 (h0+h1)   p5: B(2i+2)->buf0 (h0+h1)
// Gates at p3/p7: vmcnt(0) (all 4 half-tiles of the next tile are read at the
// next phase; drained loads were issued 2-3 phases earlier -> latency hidden).
__global__ __launch_bounds__(512, 2) void gemm8p_kernel(
    const u16* __restrict__ A, const u16* __restrict__ B,
    float* __restrict__ C, int N, int K)
{
  __shared__ u16 smem[65536];   // 128 KB

  const int tid  = threadIdx.x;
  const int lane = tid & 63;
  const int wid  = tid >> 6;
  const int wm = wid >> 2, wn = wid & 3;
  int bx = blockIdx.x, by = blockIdx.y;
  swz_block(bx, by);
  const int m0 = by * 256, n0 = bx * 256;
  const int nTiles = K >> 6;          // K-tiles of 64
  const int nIter  = K >> 7;          // 2 K-tiles per iteration

  f32x4 acc[8][4] = {};
  bf16x8 afr[4][2], bfr[2][2];

  // stage one half-tile (128 rows x 64 K): 2 x gload_lds16 per thread.
  auto stageHT = [&](int ab, int buf, int half, int ktile) {
    const int kt = ktile < nTiles ? ktile : nTiles - 1;
    const int k0 = kt << 6;
    const u16* __restrict__ src = ab ? B : A;
    const int g0 = (ab ? n0 : m0) + half * 128;
    const int baseu = ((buf * 2 + ab) * 2 + half) * 8192;
#pragma unroll
    for (int L = 0; L < 2; ++L) {
      const int s = L * 512 + tid;
      const int r = s >> 3, cs = s & 7;
      const int csg = cs ^ (r & 7);
      async16(smem + baseu + (L * 512 + (tid & ~63)) * 8,
              src + (size_t)(g0 + r) * K + k0 + csg * 8);
    }
  };
  auto ldA = [&](int buf, int mi, int ks) -> bf16x8 {
    const int rA = wm * 128 + mi * 16 + (lane & 15);
    const int h = rA >> 7, rl = rA & 127;
    const int cs = (ks * 4 + (lane >> 4)) ^ (rl & 7);
    return *(const bf16x8*)&smem[((buf * 2 + 0) * 2 + h) * 8192 + rl * 64 + cs * 8];
  };
  auto ldB = [&](int buf, int ni, int ks) -> bf16x8 {
    const int rB = wn * 64 + ni * 16 + (lane & 15);
    const int h = rB >> 7, rl = rB & 127;
    const int cs = (ks * 4 + (lane >> 4)) ^ (rl & 7);
    return *(const bf16x8*)&smem[((buf * 2 + 1) * 2 + h) * 8192 + rl * 64 + cs * 8];
  };

  // prologue: tile0 -> buf0 (A h0/h1, B h0/h1), full drain, barrier
  stageHT(0, 0, 0, 0); stageHT(0, 0, 1, 0);
  stageHT(1, 0, 0, 0); stageHT(1, 0, 1, 0);
  asm volatile("s_waitcnt vmcnt(0)" ::: "memory");
  __builtin_amdgcn_sched_barrier(0);
  __builtin_amdgcn_s_barrier();
  __builtin_amdgcn_sched_barrier(0);

  for (int i = 0; i < nIter; ++i) {
    const int t2 = 2 * i;
#pragma unroll
    for (int p = 0; p < 8; ++p) {
      const int pm = p & 3, bufC = p >> 2;
      const int miB = (pm >> 1) * 4, niB = (pm & 1) * 2;
      // register subtile loads (ds_read_b128, swizzled)
      if ((pm & 1) == 0) {
#pragma unroll
        for (int m = 0; m < 4; ++m)
#pragma unroll
          for (int ks = 0; ks < 2; ++ks)
            afr[m][ks] = ldA(bufC, miB + m, ks);
      }
#pragma unroll
      for (int n = 0; n < 2; ++n)
#pragma unroll
        for (int ks = 0; ks < 2; ++ks)
          bfr[n][ks] = ldB(bufC, niB + n, ks);
      // race-free staging (see header table)
      if (p == 0)      { stageHT(0, 1, 0, t2 + 1); stageHT(0, 1, 1, t2 + 1); }
      else if (p == 1) { stageHT(1, 1, 0, t2 + 1); stageHT(1, 1, 1, t2 + 1); }
      else if (p == 4) { stageHT(0, 0, 0, t2 + 2); stageHT(0, 0, 1, t2 + 2); }
      else if (p == 5) { stageHT(1, 0, 0, t2 + 2); stageHT(1, 0, 1, t2 + 2); }
      __builtin_amdgcn_sched_barrier(0);
      __builtin_amdgcn_s_barrier();
      __builtin_amdgcn_sched_barrier(0);
      __builtin_amdgcn_s_setprio(1);
#pragma unroll
      for (int m = 0; m < 4; ++m)
#pragma unroll
        for (int n = 0; n < 2; ++n)
#pragma unroll
          for (int ks = 0; ks < 2; ++ks)
            acc[miB + m][niB + n] = __builtin_amdgcn_mfma_f32_16x16x32_bf16(
                afr[m][ks], bfr[n][ks], acc[miB + m][niB + n], 0, 0, 0);
      __builtin_amdgcn_s_setprio(0);
      if (pm == 3)                    // gate: next tile's 4 half-tiles landed
        asm volatile("s_waitcnt vmcnt(0)" ::: "memory");
      __builtin_amdgcn_sched_barrier(0);
      __builtin_amdgcn_s_barrier();
      __builtin_amdgcn_sched_barrier(0);
    }
  }
  asm volatile("s_waitcnt vmcnt(0)" ::: "memory");   // drain tail stages

  // epilogue: C row = (lane>>4)*4 + r2, col = lane&15 per fragment
#pragma unroll
  for (int mi = 0; mi < 8; ++mi) {
    const int rb = m0 + wm * 128 + mi * 16 + (lane >> 4) * 4;
#pragma unroll
    for (int ni = 0; ni < 4; ++ni) {
      const int col = n0 + wn * 64 + ni * 16 + (lane & 15);
#pragma unroll
      for (int r2 = 0; r2 < 4; ++r2)
        C[(size_t)(rb + r2) * N + col] = acc[mi][ni][r2];
    }
  }
}

// ------- GEMM 1-pass bf16 128x128 (down-proj; grid too small for 256 tiles) -------
template<int BK>
__global__ __launch_bounds__(256) void gemm_bt(
    const u16* __restrict__ A, const u16* __restrict__ B,
    float* __restrict__ C, int N, int K)
{
  constexpr int TILE = 128 * BK;
  __shared__ u16 smem[2 * TILE];
  u16* sA = smem;
  u16* sB = smem + TILE;

  const int tid  = threadIdx.x;
  const int lane = tid & 63;
  const int wave = tid >> 6;
  const int wr = wave >> 1, wc = wave & 1;
  int bx = blockIdx.x, by = blockIdx.y;
  swz_block(bx, by);
  const int m0 = by * 128, n0 = bx * 128;

  f32x4 acc[4][4] = {};
  constexpr int SPR   = BK / 8;
  constexpr int ITERS = (128 * SPR) / 256;

  for (int k0 = 0; k0 < K; k0 += BK) {
#pragma unroll
    for (int i = 0; i < ITERS; ++i) {
      const int slot = i * 256 + tid;
      const int r = slot / SPR, cc = slot % SPR;
      const int uni = (i * 256 + wave * 64) * 8;
      async16(sA + uni, A + (size_t)(m0 + r) * K + k0 + cc * 8);
      async16(sB + uni, B + (size_t)(n0 + r) * K + k0 + cc * 8);
    }
    __syncthreads();

#pragma unroll
    for (int ks = 0; ks < BK / 32; ++ks) {
      const int kb = ks * 32 + (lane >> 4) * 8;
      bf16x8 a[4], b[4];
#pragma unroll
      for (int i = 0; i < 4; ++i) {
        a[i] = *(const bf16x8*)&sA[(wr * 64 + i * 16 + (lane & 15)) * BK + kb];
        b[i] = *(const bf16x8*)&sB[(wc * 64 + i * 16 + (lane & 15)) * BK + kb];
      }
#pragma unroll
      for (int mi = 0; mi < 4; ++mi)
#pragma unroll
        for (int ni = 0; ni < 4; ++ni)
          acc[mi][ni] = __builtin_amdgcn_mfma_f32_16x16x32_bf16(a[mi], b[ni], acc[mi][ni], 0, 0, 0);
    }
    __syncthreads();
  }

#pragma unroll
  for (int mi = 0; mi < 4; ++mi) {
    const int rbase = m0 + wr * 64 + mi * 16 + (lane >> 4) * 4;
#pragma unroll
    for (int ni = 0; ni < 4; ++ni) {
      const int col = n0 + wc * 64 + ni * 16 + (lane & 15);
#pragma unroll
      for (int r2 = 0; r2 < 4; ++r2)
        C[(size_t)(rbase + r2) * N + col] = acc[mi][ni][r2];
    }
  }
}

// ---------------- per-row top-k select (register z, 4-wide replica dots) ------------
// [R11-validated, unchanged]
__global__ __launch_bounds__(256) void select7_kernel(
    const float* __restrict__ zg, const float* __restrict__ xin,
    const float* __restrict__ W1,
    u16* __restrict__ sbuf, const int* __restrict__ kptr)
{
  const int row = blockIdx.x, tid = threadIdx.x;
  const int lane = tid & 63, wave = tid >> 6;
  const int k = *kptr;

  __shared__ float xrow[1024];
  __shared__ float sact[4096];
  __shared__ unsigned char flag[4096];
  __shared__ int wsum[4];
  __shared__ int s_nb;
  __shared__ int band_idx[256];
  __shared__ u32 band_key[256];
  __shared__ float band_act[256];

  const float* zrow = zg + (size_t)row * 8192;
  const float* grow = zrow + 4096;

  float zreg[16];
#pragma unroll
  for (int q = 0; q < 4; ++q) {
    const float4 v = *(const float4*)&zrow[q * 1024 + tid * 4];
    zreg[q * 4 + 0] = v.x; zreg[q * 4 + 1] = v.y;
    zreg[q * 4 + 2] = v.z; zreg[q * 4 + 3] = v.w;
  }
  *(float4*)&xrow[tid * 4] = *(const float4*)&xin[(size_t)row * 1024 + tid * 4];
  *(u32*)&flag[tid * 4] = 0u;
  *(u32*)&flag[1024 + tid * 4] = 0u;
  *(u32*)&flag[2048 + tid * 4] = 0u;
  *(u32*)&flag[3072 + tid * 4] = 0u;
  if (tid == 0) s_nb = 0;
  __syncthreads();

  // 20-step MSB bisection for ~kth largest (register compares; quantum 2.4e-4)
  u32 prefix = 0;
  for (int step = 0; step < 20; ++step) {
    const u32 c = prefix | (1u << (31 - step));
    const float zc = unfkey(c);
    int cnt = 0;
#pragma unroll
    for (int i = 0; i < 16; ++i) cnt += (zreg[i] >= zc) ? 1 : 0;
    for (int off = 32; off; off >>= 1) cnt += __shfl_xor(cnt, off);
    if (lane == 0) wsum[wave] = cnt;
    __syncthreads();
    const int tot = wsum[0] + wsum[1] + wsum[2] + wsum[3];
    if (tot >= k) prefix = c;
    __syncthreads();
  }
  const float tau = unfkey(prefix);
  const float BANDW = 1.5e-2f;
  const float thi = tau + BANDW, tlo = tau - BANDW;

  int cntD = 0;
#pragma unroll
  for (int q = 0; q < 4; ++q)
#pragma unroll
    for (int j = 0; j < 4; ++j) {
      const int f = q * 1024 + tid * 4 + j;
      const float zv = zreg[q * 4 + j];
      if (zv > thi) { flag[f] = 1; ++cntD; }
      else if (zv >= tlo) {
        const int p = atomicAdd(&s_nb, 1);
        if (p < 256) band_idx[p] = f;
      }
    }
  for (int off = 32; off; off >>= 1) cntD += __shfl_xor(cntD, off);
  if (lane == 0) wsum[wave] = cntD;
  __syncthreads();
  const int D = wsum[0] + wsum[1] + wsum[2] + wsum[3];
  const int nb = (s_nb < 256) ? s_nb : 256;
  const int need = k - D;

  // 4-wide numpy-replica dots (SSE lane chains, exact hadd combine)
  {
    const int gi = tid >> 2, l = tid & 3;
    const int wl = lane & ~3;
    for (int i = gi; i < nb; i += 64) {
      const int f = band_idx[i];
      const float* wr = W1 + (size_t)f * 1024;
      float v = 0.f;
#pragma unroll 8
      for (int b = 0; b < 1024; b += 16) {
        float t = __fadd_rn(__fmul_rn(xrow[b + 12 + l], wr[b + 12 + l]), v);
        t = __fadd_rn(__fmul_rn(xrow[b + 8 + l],  wr[b + 8 + l]),  t);
        t = __fadd_rn(__fmul_rn(xrow[b + 4 + l],  wr[b + 4 + l]),  t);
        v = __fadd_rn(__fmul_rn(xrow[b + 0 + l],  wr[b + 0 + l]),  t);
      }
      const float c0 = __shfl(v, wl + 0);
      const float c1 = __shfl(v, wl + 1);
      const float c2 = __shfl(v, wl + 2);
      const float c3 = __shfl(v, wl + 3);
      if (l == 0) {
        const float zrep = __fadd_rn(__fadd_rn(c0, c1), __fadd_rn(c2, c3));
        const double zd = (double)zrep;
        const float a = (float)(zd / (1.0 + exp(-zd)));
        band_act[i] = a;
        band_key[i] = fkey(a);
      }
    }
  }
  __syncthreads();

  // stable rank (exact key desc, index asc); selected band: flag=2, sact <- act
  for (int i = tid; i < nb; i += 256) {
    const u32 ki = band_key[i];
    const int fi = band_idx[i];
    int rank = 0;
    for (int j = 0; j < nb; ++j) {
      const u32 kj = band_key[j];
      rank += (kj > ki || (kj == ki && band_idx[j] < fi)) ? 1 : 0;
    }
    if (rank < need) { flag[fi] = 2; sact[fi] = band_act[i]; }
  }
  __syncthreads();

  u16* srow = sbuf + (size_t)row * 4096;
#pragma unroll
  for (int q = 0; q < 4; ++q) {
    const int f0 = q * 1024 + tid * 4;
    const float4 gv = *(const float4*)&grow[f0];
    const float gvv[4] = { gv.x, gv.y, gv.z, gv.w };
    const u32 fl = *(const u32*)&flag[f0];
    u16 out[4];
#pragma unroll
    for (int j = 0; j < 4; ++j) {
      const u32 fj = (fl >> (8 * j)) & 0xFF;
      float sval = 0.f;
      if (fj == 2) {
        sval = sact[f0 + j] * gvv[j];
      } else if (fj == 1) {
        const float zz = zreg[q * 4 + j];
        sval = (zz / (1.f + expf(-zz))) * gvv[j];
      }
      out[j] = f2bf(sval);
    }
    *(ushort4*)&srow[f0] = make_ushort4(out[0], out[1], out[2], out[3]);
  }
}

// ---------------- launch ----------------
extern "C" void kernel_launch(void* const* d_in, const int* in_sizes, int n_in,
                              void* d_out, int out_size, void* d_ws, size_t ws_size,
                              hipStream_t stream)
{
  const float* x  = (const float*)d_in[0];
  const float* W1 = (const float*)d_in[1];
  const float* W2 = (const float*)d_in[2];
  const float* Wo = (const float*)d_in[3];
  const int* kptr = (const int*)d_in[4];

  const int DM = 1024, DF = 4096;
  const int M = in_sizes[0] / DM;   // 8192 rows
  const size_t nX = (size_t)M * DM, nW = (size_t)DF * DM, nWo = (size_t)DM * DF;

  // fixed bf16 buffers: x, [W1;W2] concat, Wo
  char* w = (char*)d_ws;
  u16* x_hi   = (u16*)w;  w += nX * 2;
  u16* w12_hi = (u16*)w;  w += 2 * nW * 2;
  u16* wo_hi  = (u16*)w;  w += nWo * 2;
  const size_t fixed_bytes = (size_t)(w - (char*)d_ws);

  // per-chunk: zg (8 B/DF-elem) + s (2 B/DF-elem) = 10 B/elem
  int nch = 1;
  while (nch < 64) {
    const size_t per = (size_t)(M / nch) * DF * 10;
    if (fixed_bytes + per <= ws_size) break;
    nch *= 2;
  }
  const int Mc = M / nch;

  float* zgbuf = (float*)w;
  u16*   sbuf  = (u16*)(w + (size_t)Mc * DF * 8);

  split1_kernel<<<dim3((int)((nX + 255) / 256)), 256, 0, stream>>>(x, x_hi, (int)nX);
  split1_kernel<<<dim3((int)((nW + 255) / 256)), 256, 0, stream>>>(W1, w12_hi, (int)nW);
  split1_kernel<<<dim3((int)((nW + 255) / 256)), 256, 0, stream>>>(W2, w12_hi + nW, (int)nW);
  split1_kernel<<<dim3((int)((nWo + 255) / 256)), 256, 0, stream>>>(Wo, wo_hi, (int)nWo);

  for (int ch = 0; ch < nch; ++ch) {
    const size_t ro = (size_t)ch * Mc;
    // [z|gate] = x @ [W1;W2]^T  (8-phase 256^2 GEMM, N=8192)
    gemm8p_kernel<<<dim3(2 * DF / 256, Mc / 256), 512, 0, stream>>>(
        x_hi + ro * DM, w12_hi, zgbuf, 2 * DF, DM);
    // top-k: bisection + wide band + 4-wide replica keys; writes s (bf16)
    select7_kernel<<<dim3(Mc), 256, 0, stream>>>(
        zgbuf, x + ro * DM, W1, sbuf, kptr);
    // out = s @ Wo^T (1-pass bf16, 128^2)
    gemm_bt<64><<<dim3(DM / 128, Mc / 128), 256, 0, stream>>>(
        sbuf, wo_hi, (float*)d_out + ro * DM, DM, DF);
  }
}

// Round 14
// 647.416 us; speedup vs baseline: 1.5923x; 1.0723x over previous
//
#include <hip/hip_runtime.h>
#include <stdint.h>

#define DEV __device__ __forceinline__

using f32x4  = __attribute__((ext_vector_type(4))) float;
using bf16x8 = __attribute__((ext_vector_type(8))) short;
typedef unsigned short u16;
typedef unsigned int   u32;

typedef const __attribute__((address_space(1))) void* gptr_t;
typedef __attribute__((address_space(3))) void*       lptr_t;

DEV u16 f2bf(float f) {               // RTNE float -> bf16 bits
  union { float f; u32 u; } v; v.f = f;
  u32 lsb = (v.u >> 16) & 1u;
  v.u += 0x7fffu + lsb;
  return (u16)(v.u >> 16);
}
DEV float bf2f(u16 h) {
  union { u32 u; float f; } v; v.u = ((u32)h) << 16;
  return v.f;
}
DEV void async16(void* lds, const void* g) {
  __builtin_amdgcn_global_load_lds((gptr_t)(uintptr_t)g,
                                   (lptr_t)(u32)(uintptr_t)lds, 16, 0, 0);
}
// monotone float->uint key (ascending order preserved); bijective
DEV u32 fkey(float v) {
  u32 u = __float_as_uint(v);
  return u ^ ((u & 0x80000000u) ? 0xFFFFFFFFu : 0x80000000u);
}
DEV float unfkey(u32 key) {
  const u32 ub = (key & 0x80000000u) ? (key ^ 0x80000000u) : ~key;
  return __uint_as_float(ub);
}

// ---------------- split kernels: fp32 -> bf16 (hi, optional lo) ----------------
__global__ __launch_bounds__(256) void split1_kernel(const float* __restrict__ src,
                                                     u16* __restrict__ hi, int n) {
  int i = blockIdx.x * 256 + threadIdx.x;
  if (i >= n) return;
  hi[i] = f2bf(src[i]);
}
__global__ __launch_bounds__(256) void split2_kernel(const float* __restrict__ src,
                                                     u16* __restrict__ hi, u16* __restrict__ lo, int n) {
  int i = blockIdx.x * 256 + threadIdx.x;
  if (i >= n) return;
  float v = src[i];
  u16 h = f2bf(v);
  hi[i] = h;
  lo[i] = f2bf(v - bf2f(h));
}

// XCD-aware block swizzle (nwg % 8 == 0 for all our grids)
DEV void swz_block(int& bx, int& by) {
  const int gx = gridDim.x, nwg = gx * gridDim.y;
  const int lid = by * gx + bx;
  const int cpx = nwg >> 3;
  const int swz = (lid & 7) * cpx + (lid >> 3);
  bx = swz % gx; by = swz / gx;
}

// ======= 8-phase 256x256 GEMM, segmented-K (R13 race-free schedule, verified) ======
// C = sum_seg Aseg * Bseg^T over NSEG K-segments of length K each.
//   z (NSEG=3): [xh|xh|xl] . [W1h|W1l|W1h]  — Markidis 3-pass, hard err <= ~1e-4
//   gate (NSEG=1): xh . W2h, OUTBF16 epilogue
// 512 threads = 8 waves (2M x 4N); LDS 128 KB; swizzle cs ^= (row&7) on global
// source + ds_read; stages p0/p1 -> buf1(t+1), p4/p5 -> buf0(t+2); vmcnt(0)
// gates at p3/p7 (loads issued 2-3 phases earlier -> latency hidden).
template<int K, int NSEG, bool OUTBF16>
__global__ __launch_bounds__(512, 2) void gemm8p_kernel(
    const u16* __restrict__ A0, const u16* __restrict__ A1, const u16* __restrict__ A2,
    const u16* __restrict__ B0, const u16* __restrict__ B1, const u16* __restrict__ B2,
    void* __restrict__ Cout, int N)
{
  __shared__ u16 smem[65536];   // 128 KB

  const int tid  = threadIdx.x;
  const int lane = tid & 63;
  const int wid  = tid >> 6;
  const int wm = wid >> 2, wn = wid & 3;
  int bx = blockIdx.x, by = blockIdx.y;
  swz_block(bx, by);
  const int m0 = by * 256, n0 = bx * 256;
  constexpr int TPS    = K >> 6;            // tiles per segment
  constexpr int nTiles = NSEG * TPS;
  constexpr int nIter  = nTiles / 2;

  f32x4 acc[8][4] = {};
  bf16x8 afr[4][2], bfr[2][2];

  auto stageHT = [&](int ab, int buf, int half, int ktile) {
    const int kt  = ktile < nTiles ? ktile : nTiles - 1;
    const int seg = kt / TPS;
    const int k0  = (kt - seg * TPS) << 6;
    const u16* __restrict__ src =
        ab ? (seg == 0 ? B0 : seg == 1 ? B1 : B2)
           : (seg == 0 ? A0 : seg == 1 ? A1 : A2);
    const int g0 = (ab ? n0 : m0) + half * 128;
    const int baseu = ((buf * 2 + ab) * 2 + half) * 8192;
#pragma unroll
    for (int L = 0; L < 2; ++L) {
      const int s = L * 512 + tid;
      const int r = s >> 3, cs = s & 7;
      const int csg = cs ^ (r & 7);
      async16(smem + baseu + (L * 512 + (tid & ~63)) * 8,
              src + (size_t)(g0 + r) * K + k0 + csg * 8);
    }
  };
  auto ldA = [&](int buf, int mi, int ks) -> bf16x8 {
    const int rA = wm * 128 + mi * 16 + (lane & 15);
    const int h = rA >> 7, rl = rA & 127;
    const int cs = (ks * 4 + (lane >> 4)) ^ (rl & 7);
    return *(const bf16x8*)&smem[((buf * 2 + 0) * 2 + h) * 8192 + rl * 64 + cs * 8];
  };
  auto ldB = [&](int buf, int ni, int ks) -> bf16x8 {
    const int rB = wn * 64 + ni * 16 + (lane & 15);
    const int h = rB >> 7, rl = rB & 127;
    const int cs = (ks * 4 + (lane >> 4)) ^ (rl & 7);
    return *(const bf16x8*)&smem[((buf * 2 + 1) * 2 + h) * 8192 + rl * 64 + cs * 8];
  };

  // prologue: tile0 -> buf0 (A h0/h1, B h0/h1), full drain, barrier
  stageHT(0, 0, 0, 0); stageHT(0, 0, 1, 0);
  stageHT(1, 0, 0, 0); stageHT(1, 0, 1, 0);
  asm volatile("s_waitcnt vmcnt(0)" ::: "memory");
  __builtin_amdgcn_sched_barrier(0);
  __builtin_amdgcn_s_barrier();
  __builtin_amdgcn_sched_barrier(0);

  for (int i = 0; i < nIter; ++i) {
    const int t2 = 2 * i;
#pragma unroll
    for (int p = 0; p < 8; ++p) {
      const int pm = p & 3, bufC = p >> 2;
      const int miB = (pm >> 1) * 4, niB = (pm & 1) * 2;
      if ((pm & 1) == 0) {
#pragma unroll
        for (int m = 0; m < 4; ++m)
#pragma unroll
          for (int ks = 0; ks < 2; ++ks)
            afr[m][ks] = ldA(bufC, miB + m, ks);
      }
#pragma unroll
      for (int n = 0; n < 2; ++n)
#pragma unroll
        for (int ks = 0; ks < 2; ++ks)
          bfr[n][ks] = ldB(bufC, niB + n, ks);
      // race-free staging (R13-verified table)
      if (p == 0)      { stageHT(0, 1, 0, t2 + 1); stageHT(0, 1, 1, t2 + 1); }
      else if (p == 1) { stageHT(1, 1, 0, t2 + 1); stageHT(1, 1, 1, t2 + 1); }
      else if (p == 4) { stageHT(0, 0, 0, t2 + 2); stageHT(0, 0, 1, t2 + 2); }
      else if (p == 5) { stageHT(1, 0, 0, t2 + 2); stageHT(1, 0, 1, t2 + 2); }
      __builtin_amdgcn_sched_barrier(0);
      __builtin_amdgcn_s_barrier();
      __builtin_amdgcn_sched_barrier(0);
      __builtin_amdgcn_s_setprio(1);
#pragma unroll
      for (int m = 0; m < 4; ++m)
#pragma unroll
        for (int n = 0; n < 2; ++n)
#pragma unroll
          for (int ks = 0; ks < 2; ++ks)
            acc[miB + m][niB + n] = __builtin_amdgcn_mfma_f32_16x16x32_bf16(
                afr[m][ks], bfr[n][ks], acc[miB + m][niB + n], 0, 0, 0);
      __builtin_amdgcn_s_setprio(0);
      if (pm == 3)
        asm volatile("s_waitcnt vmcnt(0)" ::: "memory");
      __builtin_amdgcn_sched_barrier(0);
      __builtin_amdgcn_s_barrier();
      __builtin_amdgcn_sched_barrier(0);
    }
  }
  asm volatile("s_waitcnt vmcnt(0)" ::: "memory");

#pragma unroll
  for (int mi = 0; mi < 8; ++mi) {
    const int rb = m0 + wm * 128 + mi * 16 + (lane >> 4) * 4;
#pragma unroll
    for (int ni = 0; ni < 4; ++ni) {
      const int col = n0 + wn * 64 + ni * 16 + (lane & 15);
#pragma unroll
      for (int r2 = 0; r2 < 4; ++r2) {
        if constexpr (OUTBF16)
          ((u16*)Cout)[(size_t)(rb + r2) * N + col] = f2bf(acc[mi][ni][r2]);
        else
          ((float*)Cout)[(size_t)(rb + r2) * N + col] = acc[mi][ni][r2];
      }
    }
  }
}

// ------- GEMM 1-pass bf16 128x128 (down-proj) -------
template<int BK>
__global__ __launch_bounds__(256) void gemm_bt(
    const u16* __restrict__ A, const u16* __restrict__ B,
    float* __restrict__ C, int N, int K)
{
  constexpr int TILE = 128 * BK;
  __shared__ u16 smem[2 * TILE];
  u16* sA = smem;
  u16* sB = smem + TILE;

  const int tid  = threadIdx.x;
  const int lane = tid & 63;
  const int wave = tid >> 6;
  const int wr = wave >> 1, wc = wave & 1;
  int bx = blockIdx.x, by = blockIdx.y;
  swz_block(bx, by);
  const int m0 = by * 128, n0 = bx * 128;

  f32x4 acc[4][4] = {};
  constexpr int SPR   = BK / 8;
  constexpr int ITERS = (128 * SPR) / 256;

  for (int k0 = 0; k0 < K; k0 += BK) {
#pragma unroll
    for (int i = 0; i < ITERS; ++i) {
      const int slot = i * 256 + tid;
      const int r = slot / SPR, cc = slot % SPR;
      const int uni = (i * 256 + wave * 64) * 8;
      async16(sA + uni, A + (size_t)(m0 + r) * K + k0 + cc * 8);
      async16(sB + uni, B + (size_t)(n0 + r) * K + k0 + cc * 8);
    }
    __syncthreads();

#pragma unroll
    for (int ks = 0; ks < BK / 32; ++ks) {
      const int kb = ks * 32 + (lane >> 4) * 8;
      bf16x8 a[4], b[4];
#pragma unroll
      for (int i = 0; i < 4; ++i) {
        a[i] = *(const bf16x8*)&sA[(wr * 64 + i * 16 + (lane & 15)) * BK + kb];
        b[i] = *(const bf16x8*)&sB[(wc * 64 + i * 16 + (lane & 15)) * BK + kb];
      }
#pragma unroll
      for (int mi = 0; mi < 4; ++mi)
#pragma unroll
        for (int ni = 0; ni < 4; ++ni)
          acc[mi][ni] = __builtin_amdgcn_mfma_f32_16x16x32_bf16(a[mi], b[ni], acc[mi][ni], 0, 0, 0);
    }
    __syncthreads();
  }

#pragma unroll
  for (int mi = 0; mi < 4; ++mi) {
    const int rbase = m0 + wr * 64 + mi * 16 + (lane >> 4) * 4;
#pragma unroll
    for (int ni = 0; ni < 4; ++ni) {
      const int col = n0 + wc * 64 + ni * 16 + (lane & 15);
#pragma unroll
      for (int r2 = 0; r2 < 4; ++r2)
        C[(size_t)(rbase + r2) * N + col] = acc[mi][ni][r2];
    }
  }
}

// ---------------- per-row top-k select (3-pass z, narrow band) ----------------
// z from 3-pass GEMM: |z - z_numpy| <= ~1.5e-4 HARD (Cauchy-Schwarz on missing
// xl*W1l + tree rounding). Bisection quantum 2.4e-4. Band +/-8e-4 covers every
// selection-relevant channel with >=2x margin (invariant re-derived R14).
// Band channels re-ranked by bit-exact numpy-replica fp32 act keys (4-wide SSE
// lane chains, exact hadd combine), stable index tie-break. gate read as bf16.
__global__ __launch_bounds__(256) void select9_kernel(
    const float* __restrict__ z, const u16* __restrict__ g,
    const float* __restrict__ xin, const float* __restrict__ W1,
    u16* __restrict__ sbuf, const int* __restrict__ kptr)
{
  const int row = blockIdx.x, tid = threadIdx.x;
  const int lane = tid & 63, wave = tid >> 6;
  const int k = *kptr;

  __shared__ float xrow[1024];
  __shared__ float sact[4096];
  __shared__ unsigned char flag[4096];
  __shared__ int wsum[4];
  __shared__ int s_nb;
  __shared__ int band_idx[256];
  __shared__ u32 band_key[256];
  __shared__ float band_act[256];

  const float* zrow = z + (size_t)row * 4096;
  const u16*   grow = g + (size_t)row * 4096;

  float zreg[16];
#pragma unroll
  for (int q = 0; q < 4; ++q) {
    const float4 v = *(const float4*)&zrow[q * 1024 + tid * 4];
    zreg[q * 4 + 0] = v.x; zreg[q * 4 + 1] = v.y;
    zreg[q * 4 + 2] = v.z; zreg[q * 4 + 3] = v.w;
  }
  *(float4*)&xrow[tid * 4] = *(const float4*)&xin[(size_t)row * 1024 + tid * 4];
  *(u32*)&flag[tid * 4] = 0u;
  *(u32*)&flag[1024 + tid * 4] = 0u;
  *(u32*)&flag[2048 + tid * 4] = 0u;
  *(u32*)&flag[3072 + tid * 4] = 0u;
  if (tid == 0) s_nb = 0;
  __syncthreads();

  // 20-step MSB bisection for ~kth largest (register compares; quantum 2.4e-4)
  u32 prefix = 0;
  for (int step = 0; step < 20; ++step) {
    const u32 c = prefix | (1u << (31 - step));
    const float zc = unfkey(c);
    int cnt = 0;
#pragma unroll
    for (int i = 0; i < 16; ++i) cnt += (zreg[i] >= zc) ? 1 : 0;
    for (int off = 32; off; off >>= 1) cnt += __shfl_xor(cnt, off);
    if (lane == 0) wsum[wave] = cnt;
    __syncthreads();
    const int tot = wsum[0] + wsum[1] + wsum[2] + wsum[3];
    if (tot >= k) prefix = c;
    __syncthreads();
  }
  const float tau = unfkey(prefix);
  const float BANDW = 8e-4f;
  const float thi = tau + BANDW, tlo = tau - BANDW;

  int cntD = 0;
#pragma unroll
  for (int q = 0; q < 4; ++q)
#pragma unroll
    for (int j = 0; j < 4; ++j) {
      const int f = q * 1024 + tid * 4 + j;
      const float zv = zreg[q * 4 + j];
      if (zv > thi) { flag[f] = 1; ++cntD; }
      else if (zv >= tlo) {
        const int p = atomicAdd(&s_nb, 1);
        if (p < 256) band_idx[p] = f;
      }
    }
  for (int off = 32; off; off >>= 1) cntD += __shfl_xor(cntD, off);
  if (lane == 0) wsum[wave] = cntD;
  __syncthreads();
  const int D = wsum[0] + wsum[1] + wsum[2] + wsum[3];
  const int nb = (s_nb < 256) ? s_nb : 256;
  const int need = k - D;

  // 4-wide numpy-replica dots (SSE lane chains, exact hadd combine)
  {
    const int gi = tid >> 2, l = tid & 3;
    const int wl = lane & ~3;
    for (int i = gi; i < nb; i += 64) {
      const int f = band_idx[i];
      const float* wr = W1 + (size_t)f * 1024;
      float v = 0.f;
#pragma unroll 8
      for (int b = 0; b < 1024; b += 16) {
        float t = __fadd_rn(__fmul_rn(xrow[b + 12 + l], wr[b + 12 + l]), v);
        t = __fadd_rn(__fmul_rn(xrow[b + 8 + l],  wr[b + 8 + l]),  t);
        t = __fadd_rn(__fmul_rn(xrow[b + 4 + l],  wr[b + 4 + l]),  t);
        v = __fadd_rn(__fmul_rn(xrow[b + 0 + l],  wr[b + 0 + l]),  t);
      }
      const float c0 = __shfl(v, wl + 0);
      const float c1 = __shfl(v, wl + 1);
      const float c2 = __shfl(v, wl + 2);
      const float c3 = __shfl(v, wl + 3);
      if (l == 0) {
        const float zrep = __fadd_rn(__fadd_rn(c0, c1), __fadd_rn(c2, c3));
        const double zd = (double)zrep;
        const float a = (float)(zd / (1.0 + exp(-zd)));
        band_act[i] = a;
        band_key[i] = fkey(a);
      }
    }
  }
  __syncthreads();

  // stable rank (exact key desc, index asc); selected band: flag=2, sact <- act
  for (int i = tid; i < nb; i += 256) {
    const u32 ki = band_key[i];
    const int fi = band_idx[i];
    int rank = 0;
    for (int j = 0; j < nb; ++j) {
      const u32 kj = band_key[j];
      rank += (kj > ki || (kj == ki && band_idx[j] < fi)) ? 1 : 0;
    }
    if (rank < need) { flag[fi] = 2; sact[fi] = band_act[i]; }
  }
  __syncthreads();

  u16* srow = sbuf + (size_t)row * 4096;
#pragma unroll
  for (int q = 0; q < 4; ++q) {
    const int f0 = q * 1024 + tid * 4;
    const ushort4 gu = *(const ushort4*)&grow[f0];
    const float gvv[4] = { bf2f(gu.x), bf2f(gu.y), bf2f(gu.z), bf2f(gu.w) };
    const u32 fl = *(const u32*)&flag[f0];
    u16 out[4];
#pragma unroll
    for (int j = 0; j < 4; ++j) {
      const u32 fj = (fl >> (8 * j)) & 0xFF;
      float sval = 0.f;
      if (fj == 2) {
        sval = sact[f0 + j] * gvv[j];
      } else if (fj == 1) {
        const float zz = zreg[q * 4 + j];
        sval = (zz / (1.f + expf(-zz))) * gvv[j];
      }
      out[j] = f2bf(sval);
    }
    *(ushort4*)&srow[f0] = make_ushort4(out[0], out[1], out[2], out[3]);
  }
}

// ---------------- launch ----------------
extern "C" void kernel_launch(void* const* d_in, const int* in_sizes, int n_in,
                              void* d_out, int out_size, void* d_ws, size_t ws_size,
                              hipStream_t stream)
{
  const float* x  = (const float*)d_in[0];
  const float* W1 = (const float*)d_in[1];
  const float* W2 = (const float*)d_in[2];
  const float* Wo = (const float*)d_in[3];
  const int* kptr = (const int*)d_in[4];

  const int DM = 1024, DF = 4096;
  const int M = in_sizes[0] / DM;   // 8192 rows
  const size_t nX = (size_t)M * DM, nW = (size_t)DF * DM, nWo = (size_t)DM * DF;

  // fixed bf16 buffers: x hi/lo, W1 hi/lo, W2 hi, Wo hi
  char* w = (char*)d_ws;
  u16* x_hi  = (u16*)w;  w += nX * 2;
  u16* x_lo  = (u16*)w;  w += nX * 2;
  u16* W1_hi = (u16*)w;  w += nW * 2;
  u16* W1_lo = (u16*)w;  w += nW * 2;
  u16* W2_hi = (u16*)w;  w += nW * 2;
  u16* Wo_hi = (u16*)w;  w += nWo * 2;
  const size_t fixed_bytes = (size_t)(w - (char*)d_ws);

  // per-chunk: z fp32 (4) + g bf16 (2) + s bf16 (2) = 8 B/elem
  int nch = 1;
  while (nch < 64) {
    const size_t per = (size_t)(M / nch) * DF * 8;
    if (fixed_bytes + per <= ws_size) break;
    nch *= 2;
  }
  const int Mc = M / nch;

  float* zbuf = (float*)w;
  u16*   gbuf = (u16*)(w + (size_t)Mc * DF * 4);
  u16*   sbuf = (u16*)(w + (size_t)Mc * DF * 6);

  split2_kernel<<<dim3((int)((nX + 255) / 256)), 256, 0, stream>>>(x, x_hi, x_lo, (int)nX);
  split2_kernel<<<dim3((int)((nW + 255) / 256)), 256, 0, stream>>>(W1, W1_hi, W1_lo, (int)nW);
  split1_kernel<<<dim3((int)((nW + 255) / 256)), 256, 0, stream>>>(W2, W2_hi, (int)nW);
  split1_kernel<<<dim3((int)((nWo + 255) / 256)), 256, 0, stream>>>(Wo, Wo_hi, (int)nWo);

  for (int ch = 0; ch < nch; ++ch) {
    const size_t ro = (size_t)ch * Mc;
    // z = 3-pass split GEMM [xh|xh|xl].[W1h|W1l|W1h], K'=3072, fp32 out
    gemm8p_kernel<1024, 3, false><<<dim3(DF / 256, Mc / 256), 512, 0, stream>>>(
        x_hi + ro * DM, x_hi + ro * DM, x_lo + ro * DM,
        W1_hi, W1_lo, W1_hi, zbuf, DF);
    // gate = xh . W2h, 1-pass, bf16 out
    gemm8p_kernel<1024, 1, true><<<dim3(DF / 256, Mc / 256), 512, 0, stream>>>(
        x_hi + ro * DM, x_hi + ro * DM, x_hi + ro * DM,
        W2_hi, W2_hi, W2_hi, gbuf, DF);
    // top-k: narrow band (8e-4) + replica keys; writes s (bf16)
    select9_kernel<<<dim3(Mc), 256, 0, stream>>>(
        zbuf, gbuf, x + ro * DM, W1, sbuf, kptr);
    // out = s @ Wo^T (1-pass bf16, 128^2)
    gemm_bt<64><<<dim3(DM / 128, Mc / 128), 256, 0, stream>>>(
        sbuf, Wo_hi, (float*)d_out + ro * DM, DM, DF);
  }
}